// Round 15
// baseline (149.016 us; speedup 1.0000x reference)
//
#include <hip/hip_runtime.h>
#include <hip/hip_bf16.h>
#include <math.h>

// CapsNet dynamic routing. R15 = R14 with ALL 16 waves routing (8 per batch).
// - R14 left 4 of 16 waves idle in routing (192=3x64 alignment forced a
//   6-wave split). R15: 144 rows/wave (9x16 s-pass; b-update = 2 full
//   64-strides + exec-masked 16-row tail). rowbase=144*w8 = 0 mod 8 keeps
//   the half-XOR parity math (eB/pbS) valid per-lane.
// - Block = (j, 2 batches), 1024 thr, grid 1280, LDS 80.9 KB -> 2 blocks/CU
//   (32 waves/CU). Packed v2f math (R13), bf16 tiles + half-XOR swizzle (R6),
//   exp fused into b-update (R11), max-free softmax (R6-R14 verified).
//
// u: [256][1152][8] f32; weight: [1152][10][8][16] f32; out: [256][10][16] f32

#define IC 1152
#define OC 10
#define NB 256
#define TILE_DW (IC * 8)   // dwords per batch tile (bf16-packed)

typedef float v2f __attribute__((ext_vector_type(2)));

__device__ __forceinline__ v2f bf_v2(unsigned w) {
    v2f r = { __uint_as_float(w << 16), __uint_as_float(w & 0xFFFF0000u) };
    return r;
}
__device__ __forceinline__ unsigned pack2(float a, float b) {
    __hip_bfloat162 h = __float22bfloat162_rn(make_float2(a, b));
    return *(unsigned*)&h;
}
__device__ __forceinline__ unsigned short pack1(float a) {
    __hip_bfloat16 h = __float2bfloat16(a);
    return *(unsigned short*)&h;
}

__global__ __launch_bounds__(1024, 4)
void caps_route_kernel(const float* __restrict__ u,
                       const float* __restrict__ W,
                       float* __restrict__ out) {
    extern __shared__ unsigned smem_u[];
    unsigned* uh = smem_u;                                    // 2 tiles (73728 B)
    unsigned short* ce = (unsigned short*)(uh + 2 * TILE_DW); // [2 bt][IC] (4608 B)
    float* spart = (float*)(ce + 2 * IC);                     // [2 par][2 bt][8][20] (2560 B)

    const int t    = threadIdx.x;
    const int bx   = blockIdx.x;
    const int lane = t & 63;
    const int wid  = t >> 6;

    // XCD-aware (j, batch-pair) mapping (xcd = bx & 7 heuristic).
    int x = bx & 7, sg = bx >> 3;
    int j, p;
    if (sg < 128) { j = x; p = sg; }
    else { int s2 = sg - 128; j = 8 + (x >> 2); p = ((x & 3) << 5) + s2; }
    const int bb = p * 2;  // batches bb, bb+1

    // ---- Phase A: uhat[B][i][m] -> LDS bf16, half-XOR swizzle; packed fma ----
    {
        const int q  = t & 3;
        const int i0 = t >> 2;           // 0..255
        const int pb = (((q >> 1) ^ ((i0 >> 2) & 1)) << 2) + ((q & 1) << 1);
        const float* u0p = u + (size_t)bb * (IC * 8);

        auto stage = [&](int i) {
            const float4* wrow = (const float4*)(W + ((size_t)(i * OC + j) << 7)) + q;
            const float4 ua0 = *(const float4*)(u0p + i * 8);
            const float4 ua1 = *(const float4*)(u0p + i * 8 + 4);
            const float4 ub0 = *(const float4*)(u0p + IC * 8 + i * 8);
            const float4 ub1 = *(const float4*)(u0p + IC * 8 + i * 8 + 4);
            v2f a01 = {0.f,0.f}, a23 = {0.f,0.f};
            v2f b01 = {0.f,0.f}, b23 = {0.f,0.f};
#define ST(ux, uy, n) {                                                   \
            const float4 w4 = wrow[(n) * 4];                              \
            const v2f w01 = {w4.x, w4.y}, w23 = {w4.z, w4.w};             \
            const v2f us = {(ux), (ux)}, vs = {(uy), (uy)};               \
            a01 += us * w01; a23 += us * w23;                             \
            b01 += vs * w01; b23 += vs * w23; }
            ST(ua0.x, ub0.x, 0) ST(ua0.y, ub0.y, 1) ST(ua0.z, ub0.z, 2) ST(ua0.w, ub0.w, 3)
            ST(ua1.x, ub1.x, 4) ST(ua1.y, ub1.y, 5) ST(ua1.z, ub1.z, 6) ST(ua1.w, ub1.w, 7)
#undef ST
            const int dst = (i << 3) + pb;
            *(uint2*)&uh[dst]           = make_uint2(pack2(a01.x, a01.y), pack2(a23.x, a23.y));
            *(uint2*)&uh[TILE_DW + dst] = make_uint2(pack2(b01.x, b01.y), pack2(b23.x, b23.y));
        };
#pragma unroll
        for (int k = 0; k < 4; ++k) stage(i0 + 256 * k);
        if (i0 < IC - 1024) stage(i0 + 1024);
    }

    __syncthreads();  // B0: uhat ready

    // ---- Routing: octet w8 of batch bt owns rows [w8*144, +144) ----
    const int bt = wid >> 3;
    const int w8 = wid & 7;
    const int rowbase = w8 * 144;      // 144 = 9*16, 144 mod 8 == 0 -> parity math valid
    const unsigned* uhT = uh + bt * TILE_DW;
    unsigned short* ceT = ce + bt * IC;

    const int mqc = lane & 3;
    const int h   = lane >> 2;
    const int pbS = (((mqc >> 1) ^ ((h >> 2) & 1)) << 2) + ((mqc & 1) << 1);
    const bool eB = ((lane >> 2) & 1) != 0;
    const bool tail = (lane < 16);     // b-update k=2 covers 16 rows only

    float L[3];
#pragma unroll
    for (int k = 0; k < 3; ++k) L[k] = 0.f;
    float se = 0.f;
    float4 vq;

    for (int r = 0; r < 3; ++r) {
        // ---- s-pass over own 144 rows (c from ce for r>0; same-wave LDS) ----
        v2f aA = {0.f, 0.f}, aB = {0.f, 0.f};
        if (r == 0) {
#pragma unroll 3
            for (int k = 0; k < 9; ++k) {
                const int i = rowbase + 16 * k + h;
                const uint2 d = *(const uint2*)&uhT[(i << 3) + pbS];
                aA += bf_v2(d.x);
                aB += bf_v2(d.y);
            }
        } else {
#pragma unroll 3
            for (int k = 0; k < 9; ++k) {
                const int i = rowbase + 16 * k + h;
                const uint2 d = *(const uint2*)&uhT[(i << 3) + pbS];
                const float c = __uint_as_float(((unsigned)ceT[i]) << 16);
                const v2f cs = {c, c};
                aA += cs * bf_v2(d.x);
                aB += cs * bf_v2(d.y);
            }
        }
        float4 acc = make_float4(aA.x, aA.y, aB.x, aB.y);
#pragma unroll
        for (int o = 4; o <= 32; o <<= 1) {   // reduce over h within wave
            acc.x += __shfl_xor(acc.x, o, 64); acc.y += __shfl_xor(acc.y, o, 64);
            acc.z += __shfl_xor(acc.z, o, 64); acc.w += __shfl_xor(acc.w, o, 64);
        }
        float* spR = spart + (r & 1) * 320 + bt * 160;
        if (lane < 4) *(float4*)&spR[w8 * 20 + (lane << 2)] = acc;
        else if (r > 0 && lane == 4) spR[w8 * 20 + 16] = se;
        __syncthreads();  // B(r+1)

        // ---- combine all 8 octet partials + squash -> vq ----
        {
            float4 ss = {0.f, 0.f, 0.f, 0.f};
            float sesum = 0.f;
#pragma unroll
            for (int s8 = 0; s8 < 8; ++s8) {
                const float4 qq = *(const float4*)&spR[s8 * 20 + (mqc << 2)];
                ss.x += qq.x; ss.y += qq.y; ss.z += qq.z; ss.w += qq.w;
                sesum += spR[s8 * 20 + 16];
            }
            const float inv = (r == 0) ? (1.0f / (float)IC) : 1.0f / sesum;
            const float4 s4 = make_float4(ss.x * inv, ss.y * inv, ss.z * inv, ss.w * inv);
            float p2 = s4.x*s4.x + s4.y*s4.y + s4.z*s4.z + s4.w*s4.w;
            p2 += __shfl_xor(p2, 1, 64);
            p2 += __shfl_xor(p2, 2, 64);   // sum over mq quads
            const float sc = p2 / ((1.0f + p2) * sqrtf(p2 + 1e-8f));
            vq = make_float4(s4.x * sc, s4.y * sc, s4.z * sc, s4.w * sc);
        }

        if (r == 2) {
            if (w8 == 0 && lane < 4)
                *(float4*)&out[((size_t)(bb + bt) * OC + j) * 16 + (lane << 2)] = vq;
        } else {
            // ---- b-update fused with exp (same lane owns the row); packed dot ----
            const float4 q0 = make_float4(__shfl(vq.x,0,4), __shfl(vq.y,0,4),
                                          __shfl(vq.z,0,4), __shfl(vq.w,0,4));
            const float4 q1 = make_float4(__shfl(vq.x,1,4), __shfl(vq.y,1,4),
                                          __shfl(vq.z,1,4), __shfl(vq.w,1,4));
            const float4 q2 = make_float4(__shfl(vq.x,2,4), __shfl(vq.y,2,4),
                                          __shfl(vq.z,2,4), __shfl(vq.w,2,4));
            const float4 q3 = make_float4(__shfl(vq.x,3,4), __shfl(vq.y,3,4),
                                          __shfl(vq.z,3,4), __shfl(vq.w,3,4));
            const float4 Qa0 = eB ? q2 : q0, Qa1 = eB ? q3 : q1;
            const float4 Qb0 = eB ? q0 : q2, Qb1 = eB ? q1 : q3;
            const v2f va0 = {Qa0.x, Qa0.y}, va1 = {Qa0.z, Qa0.w};
            const v2f va2 = {Qa1.x, Qa1.y}, va3 = {Qa1.z, Qa1.w};
            const v2f vb0 = {Qb0.x, Qb0.y}, vb1 = {Qb0.z, Qb0.w};
            const v2f vb2 = {Qb1.x, Qb1.y}, vb3 = {Qb1.z, Qb1.w};
            se = 0.f;
#define BROW(i, Lk) {                                                     \
            const uint4 da = *(const uint4*)&uhT[(i) << 3];               \
            const uint4 db = *(const uint4*)&uhT[((i) << 3) + 4];         \
            v2f dp = {0.f, 0.f};                                          \
            dp += bf_v2(da.x) * va0;                                      \
            dp += bf_v2(da.y) * va1;                                      \
            dp += bf_v2(da.z) * va2;                                      \
            dp += bf_v2(da.w) * va3;                                      \
            dp += bf_v2(db.x) * vb0;                                      \
            dp += bf_v2(db.y) * vb1;                                      \
            dp += bf_v2(db.z) * vb2;                                      \
            dp += bf_v2(db.w) * vb3;                                      \
            Lk += dp.x + dp.y;                                            \
            const float ev = __expf(Lk);  /* max-free: verified R6-R14 */ \
            ceT[i] = pack1(ev);                                           \
            se += ev; }
            BROW(rowbase + lane, L[0])
            BROW(rowbase + lane + 64, L[1])
            if (tail) { BROW(rowbase + 128 + lane, L[2]) }
#undef BROW
#pragma unroll
            for (int o = 32; o >= 1; o >>= 1) se += __shfl_xor(se, o, 64);
        }
    }
}

extern "C" void kernel_launch(void* const* d_in, const int* in_sizes, int n_in,
                              void* d_out, int out_size, void* d_ws, size_t ws_size,
                              hipStream_t stream) {
    const float* u = (const float*)d_in[0];
    const float* W = (const float*)d_in[1];
    float* out = (float*)d_out;

    const size_t shmem = (size_t)2 * TILE_DW * 4   // two batch tiles (bf16)
                       + (size_t)2 * IC * 2        // ce
                       + 640 * 4;                  // spart => 80896 B (x2 = 161.8 KB <= 160 KiB pool)
    hipFuncSetAttribute((const void*)caps_route_kernel,
                        hipFuncAttributeMaxDynamicSharedMemorySize, (int)shmem);

    caps_route_kernel<<<(NB / 2) * OC, 1024, shmem, stream>>>(u, W, out);
}

// Round 16
// 118.140 us; speedup vs baseline: 1.2613x; 1.2613x over previous
//
#include <hip/hip_runtime.h>
#include <hip/hip_bf16.h>
#include <math.h>

// CapsNet dynamic routing. R16 = R15 (16-wave routing) squeezed to 32 VGPR.
// - R15 post-mortem: VGPR 36 > the 32-reg wall for 8 waves/SIMD (pool ~256
//   arch-VGPR/SIMD; R2-R5, R14-R15 all consistent) -> residency halved.
// - Fixes: (a) b-update v-broadcast via DYNAMIC-index width-4 shuffles
//   (src = eB ? swapped : identity quad), producing the 8 v2f operands
//   directly -- kills the q0..q3/Qa/Qb intermediates (~8 live VGPRs, ~12
//   VALU); (b) __launch_bounds__(1024, 8) pins the 8-wave/SIMD tier.
//   Spill tripwire: WRITE_SIZE must stay ~160 KB.
// - Geometry: block = (j, 2 batches), 1024 thr, grid 1280, LDS 80.9 KB ->
//   2 blocks/CU. Routing: 8 waves/batch, 144 rows/wave (9x16 s-pass;
//   b-update 2 full 64-strides + masked 16-row tail).
//
// u: [256][1152][8] f32; weight: [1152][10][8][16] f32; out: [256][10][16] f32

#define IC 1152
#define OC 10
#define NB 256
#define TILE_DW (IC * 8)   // dwords per batch tile (bf16-packed)

typedef float v2f __attribute__((ext_vector_type(2)));

__device__ __forceinline__ v2f bf_v2(unsigned w) {
    v2f r = { __uint_as_float(w << 16), __uint_as_float(w & 0xFFFF0000u) };
    return r;
}
__device__ __forceinline__ unsigned pack2(float a, float b) {
    __hip_bfloat162 h = __float22bfloat162_rn(make_float2(a, b));
    return *(unsigned*)&h;
}
__device__ __forceinline__ unsigned short pack1(float a) {
    __hip_bfloat16 h = __float2bfloat16(a);
    return *(unsigned short*)&h;
}

__global__ __launch_bounds__(1024, 8)
void caps_route_kernel(const float* __restrict__ u,
                       const float* __restrict__ W,
                       float* __restrict__ out) {
    extern __shared__ unsigned smem_u[];
    unsigned* uh = smem_u;                                    // 2 tiles (73728 B)
    unsigned short* ce = (unsigned short*)(uh + 2 * TILE_DW); // [2 bt][IC] (4608 B)
    float* spart = (float*)(ce + 2 * IC);                     // [2 par][2 bt][8][20] (2560 B)

    const int t    = threadIdx.x;
    const int bx   = blockIdx.x;
    const int lane = t & 63;
    const int wid  = t >> 6;

    // XCD-aware (j, batch-pair) mapping (xcd = bx & 7 heuristic).
    int x = bx & 7, sg = bx >> 3;
    int j, p;
    if (sg < 128) { j = x; p = sg; }
    else { int s2 = sg - 128; j = 8 + (x >> 2); p = ((x & 3) << 5) + s2; }
    const int bb = p * 2;  // batches bb, bb+1

    // ---- Phase A: uhat[B][i][m] -> LDS bf16, half-XOR swizzle; packed fma ----
    {
        const int q  = t & 3;
        const int i0 = t >> 2;           // 0..255
        const int pb = (((q >> 1) ^ ((i0 >> 2) & 1)) << 2) + ((q & 1) << 1);
        const float* u0p = u + (size_t)bb * (IC * 8);

        auto stage = [&](int i) {
            const float4* wrow = (const float4*)(W + ((size_t)(i * OC + j) << 7)) + q;
            const float4 ua0 = *(const float4*)(u0p + i * 8);
            const float4 ua1 = *(const float4*)(u0p + i * 8 + 4);
            const float4 ub0 = *(const float4*)(u0p + IC * 8 + i * 8);
            const float4 ub1 = *(const float4*)(u0p + IC * 8 + i * 8 + 4);
            v2f a01 = {0.f,0.f}, a23 = {0.f,0.f};
            v2f b01 = {0.f,0.f}, b23 = {0.f,0.f};
#define ST(ux, uy, n) {                                                   \
            const float4 w4 = wrow[(n) * 4];                              \
            const v2f w01 = {w4.x, w4.y}, w23 = {w4.z, w4.w};             \
            const v2f us = {(ux), (ux)}, vs = {(uy), (uy)};               \
            a01 += us * w01; a23 += us * w23;                             \
            b01 += vs * w01; b23 += vs * w23; }
            ST(ua0.x, ub0.x, 0) ST(ua0.y, ub0.y, 1) ST(ua0.z, ub0.z, 2) ST(ua0.w, ub0.w, 3)
            ST(ua1.x, ub1.x, 4) ST(ua1.y, ub1.y, 5) ST(ua1.z, ub1.z, 6) ST(ua1.w, ub1.w, 7)
#undef ST
            const int dst = (i << 3) + pb;
            *(uint2*)&uh[dst]           = make_uint2(pack2(a01.x, a01.y), pack2(a23.x, a23.y));
            *(uint2*)&uh[TILE_DW + dst] = make_uint2(pack2(b01.x, b01.y), pack2(b23.x, b23.y));
        };
#pragma unroll
        for (int k = 0; k < 4; ++k) stage(i0 + 256 * k);
        if (i0 < IC - 1024) stage(i0 + 1024);
    }

    __syncthreads();  // B0: uhat ready

    // ---- Routing: octet w8 of batch bt owns rows [w8*144, +144) ----
    const int bt = wid >> 3;
    const int w8 = wid & 7;
    const int rowbase = w8 * 144;      // 144 = 9*16, 144 mod 8 == 0 -> parity math valid
    const unsigned* uhT = uh + bt * TILE_DW;
    unsigned short* ceT = ce + bt * IC;

    const int mqc = lane & 3;
    const int h   = lane >> 2;
    const int pbS = (((mqc >> 1) ^ ((h >> 2) & 1)) << 2) + ((mqc & 1) << 1);
    const bool eB = ((lane >> 2) & 1) != 0;
    // dynamic-index broadcast sources (quad within width-4 group), eB-swapped
    const int sA0 = eB ? 2 : 0, sA1 = eB ? 3 : 1;
    const int sB0 = eB ? 0 : 2, sB1 = eB ? 1 : 3;

    float L[3];
#pragma unroll
    for (int k = 0; k < 3; ++k) L[k] = 0.f;
    float se = 0.f;
    float4 vq;

    for (int r = 0; r < 3; ++r) {
        // ---- s-pass over own 144 rows (c from ce for r>0; same-wave LDS) ----
        v2f aA = {0.f, 0.f}, aB = {0.f, 0.f};
        if (r == 0) {
#pragma unroll 3
            for (int k = 0; k < 9; ++k) {
                const int i = rowbase + 16 * k + h;
                const uint2 d = *(const uint2*)&uhT[(i << 3) + pbS];
                aA += bf_v2(d.x);
                aB += bf_v2(d.y);
            }
        } else {
#pragma unroll 3
            for (int k = 0; k < 9; ++k) {
                const int i = rowbase + 16 * k + h;
                const uint2 d = *(const uint2*)&uhT[(i << 3) + pbS];
                const float c = __uint_as_float(((unsigned)ceT[i]) << 16);
                const v2f cs = {c, c};
                aA += cs * bf_v2(d.x);
                aB += cs * bf_v2(d.y);
            }
        }
        float4 acc = make_float4(aA.x, aA.y, aB.x, aB.y);
#pragma unroll
        for (int o = 4; o <= 32; o <<= 1) {   // reduce over h within wave
            acc.x += __shfl_xor(acc.x, o, 64); acc.y += __shfl_xor(acc.y, o, 64);
            acc.z += __shfl_xor(acc.z, o, 64); acc.w += __shfl_xor(acc.w, o, 64);
        }
        float* spR = spart + (r & 1) * 320 + bt * 160;
        if (lane < 4) *(float4*)&spR[w8 * 20 + (lane << 2)] = acc;
        else if (r > 0 && lane == 4) spR[w8 * 20 + 16] = se;
        __syncthreads();  // B(r+1)

        // ---- combine all 8 octet partials + squash -> vq ----
        {
            float4 ss = {0.f, 0.f, 0.f, 0.f};
            float sesum = 0.f;
#pragma unroll
            for (int s8 = 0; s8 < 8; ++s8) {
                const float4 qq = *(const float4*)&spR[s8 * 20 + (mqc << 2)];
                ss.x += qq.x; ss.y += qq.y; ss.z += qq.z; ss.w += qq.w;
                sesum += spR[s8 * 20 + 16];
            }
            const float inv = (r == 0) ? (1.0f / (float)IC) : 1.0f / sesum;
            const float4 s4 = make_float4(ss.x * inv, ss.y * inv, ss.z * inv, ss.w * inv);
            float p2 = s4.x*s4.x + s4.y*s4.y + s4.z*s4.z + s4.w*s4.w;
            p2 += __shfl_xor(p2, 1, 64);
            p2 += __shfl_xor(p2, 2, 64);   // sum over mq quads
            const float sc = p2 / ((1.0f + p2) * sqrtf(p2 + 1e-8f));
            vq = make_float4(s4.x * sc, s4.y * sc, s4.z * sc, s4.w * sc);
        }

        if (r == 2) {
            if (w8 == 0 && lane < 4)
                *(float4*)&out[((size_t)(bb + bt) * OC + j) * 16 + (lane << 2)] = vq;
        } else {
            // ---- b-update fused with exp; v-broadcast via dynamic width-4
            //      shuffles straight into the 8 packed operands ----
            const v2f va0 = { __shfl(vq.x, sA0, 4), __shfl(vq.y, sA0, 4) };
            const v2f va1 = { __shfl(vq.z, sA0, 4), __shfl(vq.w, sA0, 4) };
            const v2f va2 = { __shfl(vq.x, sA1, 4), __shfl(vq.y, sA1, 4) };
            const v2f va3 = { __shfl(vq.z, sA1, 4), __shfl(vq.w, sA1, 4) };
            const v2f vb0 = { __shfl(vq.x, sB0, 4), __shfl(vq.y, sB0, 4) };
            const v2f vb1 = { __shfl(vq.z, sB0, 4), __shfl(vq.w, sB0, 4) };
            const v2f vb2 = { __shfl(vq.x, sB1, 4), __shfl(vq.y, sB1, 4) };
            const v2f vb3 = { __shfl(vq.z, sB1, 4), __shfl(vq.w, sB1, 4) };
            se = 0.f;
#define BROW(i, Lk) {                                                     \
            const uint4 da = *(const uint4*)&uhT[(i) << 3];               \
            const uint4 db = *(const uint4*)&uhT[((i) << 3) + 4];         \
            v2f dp = {0.f, 0.f};                                          \
            dp += bf_v2(da.x) * va0;                                      \
            dp += bf_v2(da.y) * va1;                                      \
            dp += bf_v2(da.z) * va2;                                      \
            dp += bf_v2(da.w) * va3;                                      \
            dp += bf_v2(db.x) * vb0;                                      \
            dp += bf_v2(db.y) * vb1;                                      \
            dp += bf_v2(db.z) * vb2;                                      \
            dp += bf_v2(db.w) * vb3;                                      \
            Lk += dp.x + dp.y;                                            \
            const float ev = __expf(Lk);  /* max-free: verified R6-R15 */ \
            ceT[i] = pack1(ev);                                           \
            se += ev; }
            BROW(rowbase + lane, L[0])
            BROW(rowbase + lane + 64, L[1])
            if (lane < 16) { BROW(rowbase + 128 + lane, L[2]) }
#undef BROW
#pragma unroll
            for (int o = 32; o >= 1; o >>= 1) se += __shfl_xor(se, o, 64);
        }
    }
}

extern "C" void kernel_launch(void* const* d_in, const int* in_sizes, int n_in,
                              void* d_out, int out_size, void* d_ws, size_t ws_size,
                              hipStream_t stream) {
    const float* u = (const float*)d_in[0];
    const float* W = (const float*)d_in[1];
    float* out = (float*)d_out;

    const size_t shmem = (size_t)2 * TILE_DW * 4   // two batch tiles (bf16)
                       + (size_t)2 * IC * 2        // ce
                       + 640 * 4;                  // spart => 80896 B (x2 <= 160 KiB pool)
    hipFuncSetAttribute((const void*)caps_route_kernel,
                        hipFuncAttributeMaxDynamicSharedMemorySize, (int)shmem);

    caps_route_kernel<<<(NB / 2) * OC, 1024, shmem, stream>>>(u, W, out);
}